// Round 4
// baseline (256.005 us; speedup 1.0000x reference)
//
#include <hip/hip_runtime.h>

// dense_image_warp: out[b,h,w,c] = bilinear(img, h - flow[b,h,w,0], w - flow[b,h,w,1])
// tfa semantics: floor clipped to [0, size-2], alpha clipped to [0,1].
// B=8, H=512, W=512, C=16 (fp32).
//
// Round-4 theory: dur == FETCH_SIZE / 0.93 TB/s across ALL four prior variants
// (quad / octet / nt / 2px-MLP). The binding constraint is HBM *read*
// efficiency: the ~84 MB of L3-compulsory img misses are demanded in gather
// order (random 64-B granules), which HBM services at ~0.93 TB/s.
// Fix: two-pass. Pass 1 linearly streams img+flow through L3 (MALL) at
// streaming efficiency; pass 2 (unchanged gather) then hits L3 instead of
// issuing random HBM reads. nt output stores keep the write stream from
// evicting the warmed inputs (144 MB < 256 MB L3).

constexpr int B = 8;
constexpr int H = 512;
constexpr int W = 512;
constexpr int C = 16;

typedef float f32x4 __attribute__((ext_vector_type(4)));

// ---------- Pass 1: linear L3 warm (reads only, no writes) ----------
__global__ __launch_bounds__(256) void warm_kernel(
    const float* __restrict__ img,
    const float* __restrict__ flow)
{
    const size_t tid = (size_t)blockIdx.x * blockDim.x + threadIdx.x;
    constexpr size_t IMG4  = (size_t)B * H * W * C / 4;  // 8,388,608 f32x4
    // flow adds 1,048,576 f32x4 -> total 9,437,184 threads
    f32x4 v;
    if (tid < IMG4) {
        v = reinterpret_cast<const f32x4*>(img)[tid];
    } else {
        v = reinterpret_cast<const f32x4*>(flow)[tid - IMG4];
    }
    // keep the load live without storing anything (rule: asm sink beats DCE)
    asm volatile("" :: "v"(v));
}

// ---------- Pass 2: gather (identical to round-3 structure) ----------
__global__ __launch_bounds__(256) void warp_kernel(
    const float* __restrict__ img,
    const float* __restrict__ flow,
    float* __restrict__ out)
{
    const int tid = blockIdx.x * blockDim.x + threadIdx.x;
    const int g  = tid >> 2;          // vertical pixel-pair index
    const int c0 = (tid & 3) << 2;    // channel offset: 0,4,8,12

    // g -> (b, hh, w) with hh in [0, H/2); pair rows h0 = 2*hh, h0+1
    const int w  = g & (W - 1);
    const int hh = (g >> 9) & (H / 2 - 1);
    const int b  = g >> 17;
    const int h0 = hh << 1;

    const int p0 = (b * H + h0) * W + w;   // pixel (b, h0,   w)
    const int p1 = p0 + W;                 // pixel (b, h0+1, w)

    const float2 f0 = *reinterpret_cast<const float2*>(flow + 2 * (size_t)p0);
    const float2 f1 = *reinterpret_cast<const float2*>(flow + 2 * (size_t)p1);

    // --- pixel 0 address math ---
    const float qy0 = (float)h0 - f0.x;
    const float qx0 = (float)w  - f0.y;
    const float fy0 = fminf(fmaxf(floorf(qy0), 0.0f), (float)(H - 2));
    const float fx0 = fminf(fmaxf(floorf(qx0), 0.0f), (float)(W - 2));
    const float ay0 = fminf(fmaxf(qy0 - fy0, 0.0f), 1.0f);
    const float ax0 = fminf(fmaxf(qx0 - fx0, 0.0f), 1.0f);
    const int iy0 = (int)fy0;
    const int ix0 = (int)fx0;

    // --- pixel 1 address math ---
    const float qy1 = (float)(h0 + 1) - f1.x;
    const float qx1 = (float)w        - f1.y;
    const float fy1 = fminf(fmaxf(floorf(qy1), 0.0f), (float)(H - 2));
    const float fx1 = fminf(fmaxf(floorf(qx1), 0.0f), (float)(W - 2));
    const float ay1 = fminf(fmaxf(qy1 - fy1, 0.0f), 1.0f);
    const float ax1 = fminf(fmaxf(qx1 - fx1, 0.0f), 1.0f);
    const int iy1 = (int)fy1;
    const int ix1 = (int)fx1;

    const int rowStride = W * C;  // floats per image row
    const float* base0 = img + ((size_t)((b * H + iy0) * W + ix0) * C + c0);
    const float* base1 = img + ((size_t)((b * H + iy1) * W + ix1) * C + c0);

    const f32x4 tl0 = *reinterpret_cast<const f32x4*>(base0);
    const f32x4 tr0 = *reinterpret_cast<const f32x4*>(base0 + C);
    const f32x4 bl0 = *reinterpret_cast<const f32x4*>(base0 + rowStride);
    const f32x4 br0 = *reinterpret_cast<const f32x4*>(base0 + rowStride + C);
    const f32x4 tl1 = *reinterpret_cast<const f32x4*>(base1);
    const f32x4 tr1 = *reinterpret_cast<const f32x4*>(base1 + C);
    const f32x4 bl1 = *reinterpret_cast<const f32x4*>(base1 + rowStride);
    const f32x4 br1 = *reinterpret_cast<const f32x4*>(base1 + rowStride + C);

    // Reference op order, elementwise.
    const f32x4 t0  = tl0 + ax0 * (tr0 - tl0);
    const f32x4 bo0 = bl0 + ax0 * (br0 - bl0);
    const f32x4 o0  = t0 + ay0 * (bo0 - t0);

    const f32x4 t1  = tl1 + ax1 * (tr1 - tl1);
    const f32x4 bo1 = bl1 + ax1 * (br1 - bl1);
    const f32x4 o1  = t1 + ay1 * (bo1 - t1);

    // nt: keep the 131 MB write stream from evicting the warmed inputs.
    __builtin_nontemporal_store(
        o0, reinterpret_cast<f32x4*>(out + (size_t)p0 * C + c0));
    __builtin_nontemporal_store(
        o1, reinterpret_cast<f32x4*>(out + (size_t)p1 * C + c0));
}

extern "C" void kernel_launch(void* const* d_in, const int* in_sizes, int n_in,
                              void* d_out, int out_size, void* d_ws, size_t ws_size,
                              hipStream_t stream) {
    const float* img  = (const float*)d_in[0];   // [B,H,W,C] fp32
    const float* flow = (const float*)d_in[1];   // [B,H,W,2] fp32
    float* out = (float*)d_out;                  // [B,H,W,C] fp32

    // Pass 1: warm L3 with img (128 MB) + flow (16 MB), linear & coalesced.
    {
        const size_t total4 = ((size_t)B * H * W * C + (size_t)B * H * W * 2) / 4;
        const int block = 256;
        const int grid = (int)(total4 / block);  // 36864, exact
        warm_kernel<<<grid, block, 0, stream>>>(img, flow);
    }

    // Pass 2: gather. 2 pixels per thread, 4 lanes per pixel.
    {
        const int total = B * (H / 2) * W * 4;   // 4,194,304
        const int block = 256;
        const int grid = total / block;          // 16384
        warp_kernel<<<grid, block, 0, stream>>>(img, flow, out);
    }
}